// Round 9
// baseline (524.910 us; speedup 1.0000x reference)
//
#include <hip/hip_runtime.h>
#include <hip/hip_bf16.h>
#include <cmath>

// Problem constants: B=64, N=256, IN=128, E=256, H=8, F=1024
#define BB 64
#define NNODES 256
#define INF_ 128
#define EE 256
#define HH 8
#define FFN 1024
#define BNROWS 16384   // B*N

typedef __attribute__((ext_vector_type(8))) short short8;
typedef __attribute__((ext_vector_type(4))) float floatx4;
typedef __attribute__((ext_vector_type(4))) unsigned short ushort4v;

__device__ __forceinline__ float b2f(unsigned short u) {
  union { unsigned u32; float f; } w; w.u32 = ((unsigned)u) << 16; return w.f;
}
__device__ __forceinline__ unsigned short f2b(float f) {
  union { float f; unsigned u32; } w; w.f = f;
  unsigned r = w.u32 + 0x7FFFu + ((w.u32 >> 16) & 1u);   // RNE
  return (unsigned short)(r >> 16);
}
// tanh-gelu (max abs dev from exact erf-gelu ~3e-4, far below bf16 rounding)
__device__ __forceinline__ float gelu_f(float x) {
  const float z = 0.7978845608028654f * (x + 0.044715f * x * x * x);
  const float e = __expf(2.0f * z);
  const float th = (e - 1.0f) / (e + 1.0f);
  return 0.5f * x * (1.0f + th);
}

typedef const __attribute__((address_space(1))) void GV;
typedef __attribute__((address_space(3))) void LV;

// async global->LDS: per-lane 16B source, wave-uniform LDS base (+lane*16)
__device__ __forceinline__ void gl_lds16(const unsigned short* g,
                                         unsigned short* l, int lane) {
#if __has_builtin(__builtin_amdgcn_global_load_lds)
  __builtin_amdgcn_global_load_lds((GV*)g, (LV*)l, 16, 0, 0);
#else
  *(short8*)(l + lane * 8) = *(const short8*)g;
#endif
}

// ---------------------------------------------------------------------------
// One kernel for ALL packing: transpose-cvt jobs + plain cvt jobs (C==0).
// ---------------------------------------------------------------------------
struct PackArgs {
  const float* src[12];
  unsigned short* dst[12];
  int R[12], C[12];
  int start[13];
};

__launch_bounds__(256)
__global__ void pack_kernel(PackArgs a)
{
  __shared__ float tile[32][33];
  const int bid = blockIdx.x;
  int j = 0;
  while (bid >= a.start[j + 1]) j++;
  const int lb = bid - a.start[j];
  const float* src = a.src[j];
  unsigned short* dst = a.dst[j];
  const int R = a.R[j], C = a.C[j];

  if (C == 0) {      // plain cvt, R = element count
    const int i = (lb * 256 + threadIdx.x) * 4;
    if (i >= R) return;
    floatx4 v = *(const floatx4*)(src + i);
    ushort4v o;
    #pragma unroll
    for (int k = 0; k < 4; k++) o[k] = f2b(v[k]);
    *(ushort4v*)(dst + i) = o;
    return;
  }
  const int tpr = C >> 5;
  const int c0 = (lb % tpr) * 32, r0 = (lb / tpr) * 32;
  const int tx = threadIdx.x & 31, ty = threadIdx.x >> 5;
  #pragma unroll
  for (int i = ty; i < 32; i += 8)
    tile[i][tx] = src[(long long)(r0 + i) * C + c0 + tx];
  __syncthreads();
  #pragma unroll
  for (int i = ty; i < 32; i += 8)
    dst[(long long)(c0 + i) * R + r0 + tx] = f2b(tile[tx][i]);
}

// ---------------------------------------------------------------------------
// dis = rsqrt(clip(rowsum(A),1,inf)); A = adj (f32) with diag forced to 1
// wave per row, 4 rows per block, full-chip grid.
// ---------------------------------------------------------------------------
__global__ void deg_kernel(const float* __restrict__ adj,
                           float* __restrict__ dis)
{
  const int g = blockIdx.x * 4 + (threadIdx.x >> 6);
  const int lane = threadIdx.x & 63;
  const int i = g & 255;
  floatx4 v = *(const floatx4*)(adj + (long long)g * 256 + lane * 4);
  float s = 0.f;
  #pragma unroll
  for (int jj = 0; jj < 4; jj++) {
    const int j = lane * 4 + jj;
    s += (j == i) ? 1.0f : v[jj];
  }
  #pragma unroll
  for (int off = 32; off > 0; off >>= 1) s += __shfl_xor(s, off);
  if (lane == 0) dis[g] = 1.0f / sqrtf(fmaxf(s, 1.0f));
}

// An[b,i,j] = bf16(dis_i * A_ij * dis_j)
__global__ void an_kernel(const float* __restrict__ adj,
                          const float* __restrict__ dis,
                          unsigned short* __restrict__ An)
{
  const long long base = ((long long)blockIdx.x * 256 + threadIdx.x) * 4;
  const int rowg = (int)(base >> 8);
  const int i = rowg & 255;
  const int brow = rowg & ~255;
  const int j0 = (int)(base & 255);
  const float di = dis[rowg];
  floatx4 v = *(const floatx4*)(adj + base);
  ushort4v o;
  #pragma unroll
  for (int jj = 0; jj < 4; jj++) {
    const int j = j0 + jj;
    const float a = (j == i) ? 1.0f : v[jj];
    o[jj] = f2b(di * dis[brow + j] * a);
  }
  *(ushort4v*)(An + base) = o;
}

// ---------------------------------------------------------------------------
// Batched bf16 MFMA GEMM, tile 128x128, BK=128 chunks, 512 threads (8 waves,
// 2x4), each wave 64x32 (acc[4][2]). A (M,K) rm; B (N,K) rm (always NT).
// LDS rows x 16 slots of 16B; slot s holds k-octet q = s ^ (r&7) (XOR swizzle).
// modes:
//  0: f32 store | 1: bf16 store | 2: f32 accumulate | 3: bf16 gelu(val+aux1[col])
//  5: TT store: b=row>>8,n=row&255 -> bf16 C[b*65536+col*256+n]
//  8: final:  f32 C[row*256+col] = gcn[i]+attf[i]+(val+aux1[col])*mask[row]
//  9: GCN epi (C'=U^T): token=zb*256+col, feat=row; g=relu((val+aux1[feat])*mask[token]);
//     bf16 C[token*256+feat]=g; gcn[...] (flag? += : =) g
// 12: f32 C[row*256+col] = gcn[idx] + (val + aux1[col]) * mask[row]
// 13: bf16 store of val * 0.0625  (ABH with attention scale folded)
// 15: Q'/V combined: col<2048 -> bf16 C[row*2048+col] (Q');
//     else V^T scatter: z2=(row>>8)*8+((col>>8)-8); bf16
//     aux2[z2*65536+(col&255)*256+(row&255)]
// ---------------------------------------------------------------------------
__launch_bounds__(512, 4)
__global__ void gemm_kernel(const unsigned short* __restrict__ A, int lda,
                            long long sAo, long long sAi,
                            const unsigned short* __restrict__ Bm, int ldb,
                            long long sBo, long long sBi,
                            void* __restrict__ Cv, int ldc,
                            long long sCo, long long sCi,
                            int K, int zshift, int mode, int flag,
                            const float* __restrict__ aux1,
                            const float* __restrict__ mask,
                            float* __restrict__ gcn,
                            void* __restrict__ aux2)
{
  __shared__ __align__(16) unsigned short sA[16384];   // 32KB
  __shared__ __align__(16) unsigned short sB[16384];   // 32KB

  const int t = threadIdx.x;
  const int z = blockIdx.z;
  const int zi = z & ((1 << zshift) - 1);
  const int zb = z >> zshift;
  const int m0 = blockIdx.x * 128;
  const int n0 = blockIdx.y * 128;
  A  += zb * sAo + zi * sAi;
  Bm += zb * sBo + zi * sBi;
  const long long cbase = zb * sCo + zi * sCi;

  const int lane = t & 63;
  const int w = t >> 6;              // wave 0..7
  const int wm = w >> 2, wn = w & 3; // 2 x 4
  const int lm = lane & 15, qd = lane >> 4;

  floatx4 acc[4][2] = {};

  const int sub = lane >> 4;        // 0..3
  const int qs  = lane & 15;        // slot within row
  const unsigned short* pA[4];
  const unsigned short* pB[4];
  #pragma unroll
  for (int i = 0; i < 4; i++) {
    const int d = w * 4 + i;        // DMA index 0..31
    const int r = d * 4 + sub;      // tile row 0..127
    const int co = (qs ^ (r & 7)) * 8;   // swizzled col octet (elements)
    pA[i] = A + (long long)(m0 + r) * lda + co;
    pB[i] = Bm + (long long)(n0 + r) * ldb + co;
  }

  for (int kk = 0; kk < K; kk += 128) {
    #pragma unroll
    for (int i = 0; i < 4; i++) {
      gl_lds16(pA[i] + kk, &sA[(w * 4 + i) * 512], lane);
      gl_lds16(pB[i] + kk, &sB[(w * 4 + i) * 512], lane);
    }
    __syncthreads();

    #pragma unroll
    for (int ks = 0; ks < 4; ks++) {
      short8 af[4], bg[2];
      const int q = ks * 4 + qd;          // k-octet 0..15
      #pragma unroll
      for (int mi = 0; mi < 4; mi++) {
        const int r = wm * 64 + mi * 16 + lm;
        af[mi] = *(const short8*)&sA[r * 128 + ((q ^ (r & 7)) * 8)];
      }
      #pragma unroll
      for (int ni = 0; ni < 2; ni++) {
        const int r = wn * 32 + ni * 16 + lm;
        bg[ni] = *(const short8*)&sB[r * 128 + ((q ^ (r & 7)) * 8)];
      }
      #pragma unroll
      for (int mi = 0; mi < 4; mi++)
        #pragma unroll
        for (int ni = 0; ni < 2; ni++)
          acc[mi][ni] = __builtin_amdgcn_mfma_f32_16x16x32_bf16(
              af[mi], bg[ni], acc[mi][ni], 0, 0, 0);
    }
    __syncthreads();
  }

  // ---- epilogue ----
  #pragma unroll
  for (int mi = 0; mi < 4; mi++) {
    const int row0 = m0 + wm * 64 + mi * 16 + qd * 4;
    #pragma unroll
    for (int ni = 0; ni < 2; ni++) {
      const int col = n0 + wn * 32 + ni * 16 + lm;
      floatx4 a = acc[mi][ni];
      if (mode == 0) {
        float* Cf = (float*)Cv;
        #pragma unroll
        for (int r = 0; r < 4; r++)
          Cf[cbase + (long long)(row0 + r) * ldc + col] = a[r];
      } else if (mode == 1) {
        unsigned short* Cb = (unsigned short*)Cv;
        #pragma unroll
        for (int r = 0; r < 4; r++)
          Cb[cbase + (long long)(row0 + r) * ldc + col] = f2b(a[r]);
      } else if (mode == 2) {
        float* Cf = (float*)Cv;
        #pragma unroll
        for (int r = 0; r < 4; r++)
          Cf[cbase + (long long)(row0 + r) * ldc + col] += a[r];
      } else if (mode == 3) {
        unsigned short* Cb = (unsigned short*)Cv;
        const float bv = aux1[col];
        #pragma unroll
        for (int r = 0; r < 4; r++)
          Cb[cbase + (long long)(row0 + r) * ldc + col] = f2b(gelu_f(a[r] + bv));
      } else if (mode == 5) {
        const int b = row0 >> 8, n = row0 & 255;
        ushort4v o;
        #pragma unroll
        for (int r = 0; r < 4; r++) o[r] = f2b(a[r]);
        *(ushort4v*)((unsigned short*)Cv + (long long)b * 65536 + col * 256 + n) = o;
      } else if (mode == 8) {
        float* Cf = (float*)Cv;
        const float* attf = (const float*)aux2;
        const float bv = aux1[col];
        #pragma unroll
        for (int r = 0; r < 4; r++) {
          const long long idx = (long long)(row0 + r) * 256 + col;
          Cf[idx] = gcn[idx] + attf[idx] + (a[r] + bv) * mask[row0 + r];
        }
      } else if (mode == 9) {
        const int token = zb * 256 + col;
        const float m = mask[token];
        ushort4v o; floatx4 g;
        #pragma unroll
        for (int r = 0; r < 4; r++) {
          const float v = fmaxf((a[r] + aux1[row0 + r]) * m, 0.f);
          o[r] = f2b(v); g[r] = v;
        }
        *(ushort4v*)((unsigned short*)Cv + (long long)token * 256 + row0) = o;
        float* gp = gcn + (long long)token * 256 + row0;
        if (flag) { floatx4 old = *(const floatx4*)gp; g += old; }
        *(floatx4*)gp = g;
      } else if (mode == 12) { // U = GCN + (val + bo)*mask
        float* Cf = (float*)Cv;
        const float bv = aux1[col];
        #pragma unroll
        for (int r = 0; r < 4; r++) {
          const long long idx = (long long)(row0 + r) * 256 + col;
          Cf[idx] = gcn[idx] + (a[r] + bv) * mask[row0 + r];
        }
      } else if (mode == 13) { // scaled bf16 (ABH /16)
        unsigned short* Cb = (unsigned short*)Cv;
        #pragma unroll
        for (int r = 0; r < 4; r++)
          Cb[cbase + (long long)(row0 + r) * ldc + col] = f2b(a[r] * 0.0625f);
      } else { // 15: Q' store / V^T scatter
        if (col < 2048) {
          unsigned short* Cb = (unsigned short*)Cv;
          #pragma unroll
          for (int r = 0; r < 4; r++)
            Cb[(long long)(row0 + r) * 2048 + col] = f2b(a[r]);
        } else {
          const int z2 = (row0 >> 8) * 8 + ((col >> 8) - 8);
          const int e = col & 255, n = row0 & 255;
          ushort4v o;
          #pragma unroll
          for (int r = 0; r < 4; r++) o[r] = f2b(a[r]);
          *(ushort4v*)((unsigned short*)aux2 + (long long)z2 * 65536 + e * 256 + n) = o;
        }
      }
    }
  }
}

// ---------------------------------------------------------------------------
// Fused attention v5: 64-row m-tiles (grid 4 x 512), S/Y accumulators
// halved (64 VGPR) for occupancy; Y written back through LDS for coalesced
// 16B stores. Block (mt, z=b*8+h):
//  S = Q'_tile * H_b^T ; += dist(bf16), mask, softmax; Y = P*V; Y -> Q' slab.
// ---------------------------------------------------------------------------
__launch_bounds__(512, 2)
__global__ void attn_kernel(unsigned short* __restrict__ QP,   // (16384,2048) Q' in / Y out
                            const unsigned short* __restrict__ HBF, // (16384,256)
                            const unsigned short* __restrict__ VT,  // (512,256,256)
                            const unsigned short* __restrict__ DSTB,// (64,256,256) bf16
                            const float* __restrict__ mask)
{
  __shared__ __align__(16) unsigned short sQ[4096];     // 8KB: Q' chunk / P chunk (64x64)
  __shared__ __align__(16) unsigned short sKV[16896];   // 33KB: H/V chunk (256x64) or Y staging (64x264)
  __shared__ float redm[4][64];
  __shared__ float reds[4][64];

  const int mt = blockIdx.x;         // 0..3
  const int z  = blockIdx.y;         // b*8+h
  const int b  = z >> 3, h = z & 7;
  const int t = threadIdx.x, lane = t & 63, w = t >> 6;
  const int wm = w >> 2, wn = w & 3; // 2 x 4
  const int lm = lane & 15, qd = lane >> 4;
  const int m0 = mt * 64;

  unsigned short* Qm = QP + ((long long)(b * 256 + m0)) * 2048 + h * 256;
  const unsigned short* Hb = HBF + (long long)b * 65536;
  const unsigned short* Vb = VT + (long long)z * 65536;
  const unsigned short* db = DSTB + (long long)b * 65536;
  const float* maskb = mask + b * 256;

  const int rin = lane >> 3;   // row within DMA (0..7)
  const int qs  = lane & 7;    // octet slot (0..7)

  // ---- S phase: S = Q'_tile * H_b^T, 4 chunks of 64 over e ----
  floatx4 S[2][4] = {};
  for (int c = 0; c < 4; c++) {
    const int e0 = c * 64;
    {                                        // Q' chunk: 8 DMAs (1/wave)
      const int r = w * 8 + rin;             // tile row 0..63
      gl_lds16(Qm + (long long)r * 2048 + e0 + ((qs ^ (r & 7)) * 8),
               &sQ[w * 512], lane);
    }
    #pragma unroll
    for (int i = 0; i < 4; i++) {            // H_b rows 0..255: 32 DMAs
      const int d = w * 4 + i;
      const int r = d * 8 + rin;
      gl_lds16(Hb + (long long)r * 256 + e0 + ((qs ^ (r & 7)) * 8),
               &sKV[d * 512], lane);
    }
    __syncthreads();
    #pragma unroll
    for (int ks = 0; ks < 2; ks++) {
      short8 af[2], bg4[4];
      const int o = ks * 4 + qd;
      #pragma unroll
      for (int mi = 0; mi < 2; mi++) {
        const int r = wm * 32 + mi * 16 + lm;
        af[mi] = *(const short8*)&sQ[r * 64 + ((o ^ (r & 7)) * 8)];
      }
      #pragma unroll
      for (int ni = 0; ni < 4; ni++) {
        const int r = wn * 64 + ni * 16 + lm;
        bg4[ni] = *(const short8*)&sKV[r * 64 + ((o ^ (r & 7)) * 8)];
      }
      #pragma unroll
      for (int mi = 0; mi < 2; mi++)
        #pragma unroll
        for (int ni = 0; ni < 4; ni++)
          S[mi][ni] = __builtin_amdgcn_mfma_f32_16x16x32_bf16(
              af[mi], bg4[ni], S[mi][ni], 0, 0, 0);
    }
    __syncthreads();
  }

  // ---- prefetch V chunk 0 (softmax hides the latency) ----
  #pragma unroll
  for (int i = 0; i < 4; i++) {
    const int d = w * 4 + i;
    const int r = d * 8 + rin;
    gl_lds16(Vb + (long long)r * 256 + ((qs ^ (r & 7)) * 8),
             &sKV[d * 512], lane);
  }

  // ---- softmax over cols (keys); dist is bf16 ----
  float mk[4];
  #pragma unroll
  for (int ni = 0; ni < 4; ni++) mk[ni] = maskb[wn * 64 + ni * 16 + lm];

  float lred[2][4];
  #pragma unroll
  for (int mi = 0; mi < 2; mi++) {
    #pragma unroll
    for (int r = 0; r < 4; r++) {
      const int row = wm * 32 + mi * 16 + qd * 4 + r;
      const float mq = maskb[m0 + row];
      float mx = -3e38f;
      #pragma unroll
      for (int ni = 0; ni < 4; ni++) {
        const int col = wn * 64 + ni * 16 + lm;
        const float dv = b2f(db[(long long)(m0 + row) * 256 + col]);
        const float v = (mq != 0.f && mk[ni] != 0.f) ? (S[mi][ni][r] + dv) : -1e9f;
        S[mi][ni][r] = v;
        mx = fmaxf(mx, v);
      }
      lred[mi][r] = mx;
    }
  }
  #pragma unroll
  for (int off = 1; off < 16; off <<= 1)
    #pragma unroll
    for (int mi = 0; mi < 2; mi++)
      #pragma unroll
      for (int r = 0; r < 4; r++)
        lred[mi][r] = fmaxf(lred[mi][r], __shfl_xor(lred[mi][r], off));
  if (lm == 0)
    #pragma unroll
    for (int mi = 0; mi < 2; mi++)
      #pragma unroll
      for (int r = 0; r < 4; r++)
        redm[wn][wm * 32 + mi * 16 + qd * 4 + r] = lred[mi][r];
  __syncthreads();

  #pragma unroll
  for (int mi = 0; mi < 2; mi++) {
    #pragma unroll
    for (int r = 0; r < 4; r++) {
      const int row = wm * 32 + mi * 16 + qd * 4 + r;
      const float gmax = fmaxf(fmaxf(redm[0][row], redm[1][row]),
                               fmaxf(redm[2][row], redm[3][row]));
      float s = 0.f;
      #pragma unroll
      for (int ni = 0; ni < 4; ni++) {
        const float e = __expf(S[mi][ni][r] - gmax);   // invalid -> exactly 0
        S[mi][ni][r] = e;
        s += e;
      }
      lred[mi][r] = s;
    }
  }
  #pragma unroll
  for (int off = 1; off < 16; off <<= 1)
    #pragma unroll
    for (int mi = 0; mi < 2; mi++)
      #pragma unroll
      for (int r = 0; r < 4; r++)
        lred[mi][r] += __shfl_xor(lred[mi][r], off);
  if (lm == 0)
    #pragma unroll
    for (int mi = 0; mi < 2; mi++)
      #pragma unroll
      for (int r = 0; r < 4; r++)
        reds[wn][wm * 32 + mi * 16 + qd * 4 + r] = lred[mi][r];
  __syncthreads();

  #pragma unroll
  for (int mi = 0; mi < 2; mi++) {
    #pragma unroll
    for (int r = 0; r < 4; r++) {
      const int row = wm * 32 + mi * 16 + qd * 4 + r;
      const float gs = reds[0][row] + reds[1][row] + reds[2][row] + reds[3][row];
      const float inv = 1.0f / gs;
      #pragma unroll
      for (int ni = 0; ni < 4; ni++) S[mi][ni][r] *= inv;
    }
  }

  // ---- PV phase: 4 chunks over keys; V_{c+1} issued post-barrier ----
  floatx4 Y[2][4] = {};
  for (int c = 0; c < 4; c++) {
    if (wn == c) {                          // write P chunk (the 2 waves w/ wn==c)
      #pragma unroll
      for (int mi = 0; mi < 2; mi++)
        #pragma unroll
        for (int r = 0; r < 4; r++) {
          const int row = wm * 32 + mi * 16 + qd * 4 + r;
          #pragma unroll
          for (int ni = 0; ni < 4; ni++) {
            const int kl = ni * 16 + lm;
            const int slot = (kl >> 3) ^ (row & 7);
            sQ[row * 64 + slot * 8 + (kl & 7)] = f2b(S[mi][ni][r]);
          }
        }
    }
    __syncthreads();                        // P_c visible; V_c drained
    #pragma unroll
    for (int ks = 0; ks < 2; ks++) {
      short8 af[2], bg4[4];
      const int o = ks * 4 + qd;
      #pragma unroll
      for (int mi = 0; mi < 2; mi++) {
        const int r = wm * 32 + mi * 16 + lm;
        af[mi] = *(const short8*)&sQ[r * 64 + ((o ^ (r & 7)) * 8)];
      }
      #pragma unroll
      for (int ni = 0; ni < 4; ni++) {
        const int r = wn * 64 + ni * 16 + lm;
        bg4[ni] = *(const short8*)&sKV[r * 64 + ((o ^ (r & 7)) * 8)];
      }
      #pragma unroll
      for (int mi = 0; mi < 2; mi++)
        #pragma unroll
        for (int ni = 0; ni < 4; ni++)
          Y[mi][ni] = __builtin_amdgcn_mfma_f32_16x16x32_bf16(
              af[mi], bg4[ni], Y[mi][ni], 0, 0, 0);
    }
    __syncthreads();
    if (c < 3) {
      #pragma unroll
      for (int i = 0; i < 4; i++) {
        const int d = w * 4 + i;
        const int r = d * 8 + rin;
        gl_lds16(Vb + (long long)r * 256 + (c + 1) * 64 + ((qs ^ (r & 7)) * 8),
                 &sKV[d * 512], lane);
      }
    }
  }

  // ---- epilogue: Y -> LDS (padded stride 264) -> coalesced 16B stores ----
  #pragma unroll
  for (int mi = 0; mi < 2; mi++)
    #pragma unroll
    for (int ni = 0; ni < 4; ni++) {
      const int col = wn * 64 + ni * 16 + lm;
      #pragma unroll
      for (int r = 0; r < 4; r++) {
        const int row = wm * 32 + mi * 16 + qd * 4 + r;
        sKV[row * 264 + col] = f2b(Y[mi][ni][r]);
      }
    }
  __syncthreads();
  #pragma unroll
  for (int it = 0; it < 4; it++) {
    const int idx = it * 512 + t;        // 0..2047 = 64 rows x 32 x 16B
    const int row = idx >> 5, u = idx & 31;
    short8 v = *(const short8*)&sKV[row * 264 + u * 8];
    *(short8*)(Qm + (long long)row * 2048 + u * 8) = v;
  }
}

// ---------------------------------------------------------------------------
__global__ void ln_kernel(const float* __restrict__ X,
                          const float* __restrict__ gam,
                          const float* __restrict__ bet,
                          unsigned short* __restrict__ out)
{
  const int g = blockIdx.x * 4 + (threadIdx.x >> 6);
  const int lane = threadIdx.x & 63;
  floatx4 v = *(const floatx4*)(X + (long long)g * 256 + lane * 4);
  float s = v[0] + v[1] + v[2] + v[3];
  float sq = v[0]*v[0] + v[1]*v[1] + v[2]*v[2] + v[3]*v[3];
  #pragma unroll
  for (int off = 32; off > 0; off >>= 1) {
    s  += __shfl_xor(s, off);
    sq += __shfl_xor(sq, off);
  }
  const float mean = s * (1.0f / 256.0f);
  const float var = sq * (1.0f / 256.0f) - mean * mean;
  const float rs = 1.0f / sqrtf(var + 1e-5f);
  ushort4v o;
  #pragma unroll
  for (int jj = 0; jj < 4; jj++) {
    const int c = lane * 4 + jj;
    o[jj] = f2b((v[jj] - mean) * rs * gam[c] + bet[c]);
  }
  *(ushort4v*)(out + (long long)g * 256 + lane * 4) = o;
}

// ---------------------------------------------------------------------------
static inline void launch_gemm(hipStream_t st, int M, int N, int batch,
    const void* A, int lda, long long sAo, long long sAi,
    const void* B, int ldb, long long sBo, long long sBi,
    void* C, int ldc, long long sCo, long long sCi,
    int K, int zshift, int mode, int flag,
    const float* aux1, const float* mask, float* gcn, void* aux2)
{
  dim3 grid(M / 128, N / 128, batch), blk(512);
  gemm_kernel<<<grid, blk, 0, st>>>(
      (const unsigned short*)A, lda, sAo, sAi,
      (const unsigned short*)B, ldb, sBo, sBi,
      C, ldc, sCo, sCi, K, zshift, mode, flag, aux1, mask, gcn, aux2);
}

extern "C" void kernel_launch(void* const* d_in, const int* in_sizes, int n_in,
                              void* d_out, int out_size, void* d_ws, size_t ws_size,
                              hipStream_t stream)
{
  (void)in_sizes; (void)n_in; (void)out_size;
  const float* x    = (const float*)d_in[0];
  const float* adj  = (const float*)d_in[1];
  const float* mask = (const float*)d_in[2];
  const float* dist = (const float*)d_in[3];
  const float* W1   = (const float*)d_in[4];
  const float* b1   = (const float*)d_in[5];
  const float* W2   = (const float*)d_in[6];
  const float* b2   = (const float*)d_in[7];
  const float* W3   = (const float*)d_in[8];
  const float* b3   = (const float*)d_in[9];
  const float* ln1g = (const float*)d_in[10];
  const float* ln1b = (const float*)d_in[11];
  const float* Wq   = (const float*)d_in[12];
  const float* Wk   = (const float*)d_in[13];
  const float* Wv   = (const float*)d_in[14];
  const float* Wo   = (const float*)d_in[15];
  const float* bo   = (const float*)d_in[16];
  const float* ln2g = (const float*)d_in[17];
  const float* ln2b = (const float*)d_in[18];
  const float* Wf1  = (const float*)d_in[19];
  const float* bf1  = (const float*)d_in[20];
  const float* Wf2  = (const float*)d_in[21];
  const float* bf2  = (const float*)d_in[22];

  char* w = (char*)d_ws;
  auto alloc = [&](size_t sz) { void* p = (void*)w; w += sz; return p; };
  // persistent (~61 MB)
  unsigned short* W1T   = (unsigned short*)alloc(65536);      // (256,128)
  unsigned short* W2T   = (unsigned short*)alloc(131072);     // (256,256)
  unsigned short* W3T   = (unsigned short*)alloc(131072);
  unsigned short* ABH   = (unsigned short*)alloc(1048576);    // (2048,256) = Wk_h Wq_h^T /16
  unsigned short* WVT   = (unsigned short*)alloc(1048576);    // (2048,256)
  unsigned short* WOT   = (unsigned short*)alloc(1048576);    // (256,2048)
  unsigned short* WF1T  = (unsigned short*)alloc(524288);     // (1024,256)
  unsigned short* WF2T  = (unsigned short*)alloc(524288);     // (256,1024)
  unsigned short* WQb   = (unsigned short*)alloc(1048576);    // (256,2048) plain
  unsigned short* WKb   = (unsigned short*)alloc(1048576);    // (256,2048) plain
  unsigned short* XBF   = (unsigned short*)alloc(4194304);    // (16384,128)
  unsigned short* DSTB  = (unsigned short*)alloc(8388608);    // (64,256,256) bf16 dist
  float*          GCN   = (float*)         alloc(16777216);   // (16384,256)
  float*          U     = (float*)         alloc(16777216);   // ATT f32
  unsigned short* HBF   = (unsigned short*)alloc(8388608);    // (16384,256)
  float*          DIS   = (float*)         alloc(65536);
  // scratch union (peak = attention: 134.2 MB)
  char* scratch = (char*)alloc(134217728);
  if ((size_t)(w - (char*)d_ws) > ws_size) return;
  // gcn phase views
  unsigned short* AN  = (unsigned short*)scratch;              // 8.4 MB
  unsigned short* TT  = (unsigned short*)(scratch + 8388608);  // 8.4 MB
  unsigned short* GBF = (unsigned short*)(scratch + 16777216); // 8.4 MB
  // attention phase views
  unsigned short* QPB = (unsigned short*)scratch;                 // (16384,2048) 67 MB  Q'->Y
  unsigned short* VT  = (unsigned short*)(scratch + 67108864);    // (512,256,256) 67 MB
  // ffn phase view
  unsigned short* FFB = (unsigned short*)scratch;                 // 33.6 MB

  // ---- single packing launch: 7 transposes + 4 plain cvts ----
  PackArgs pa;
  const float* srcs[11] = {W1, W2, W3, Wv, Wo, Wf1, Wf2, x, Wq, Wk, dist};
  unsigned short* dsts[11] = {W1T, W2T, W3T, WVT, WOT, WF1T, WF2T, XBF, WQb, WKb, DSTB};
  const int Rs[11] = {128, 256, 256, 256, 2048, 256, 1024,
                      BNROWS * INF_, EE * HH * EE, EE * HH * EE, BB * 65536};
  const int Cs[11] = {256, 256, 256, 2048, 256, 1024, 256, 0, 0, 0, 0};
  const int sts[12] = {0, 32, 96, 160, 672, 1184, 1440, 1696, 3744, 4256, 4768, 8864};
  for (int j = 0; j < 11; j++) {
    pa.src[j] = srcs[j]; pa.dst[j] = dsts[j]; pa.R[j] = Rs[j]; pa.C[j] = Cs[j];
  }
  for (int j = 0; j < 12; j++) pa.start[j] = sts[j];
  pack_kernel<<<8864, 256, 0, stream>>>(pa);

  // ---- adjacency normalization (full-chip grids) ----
  deg_kernel<<<4096, 256, 0, stream>>>(adj, DIS);
  an_kernel<<<4096, 256, 0, stream>>>(adj, DIS, AN);

  // ---- ABH_h = Wk_h Wq_h^T / 16  (8 heads, tiny batched GEMM) ----
  launch_gemm(stream, 256, 256, 8, WKb, 2048, 256, 0, WQb, 2048, 256, 0,
              ABH, 256, 65536, 0, 256, 0, 13, 0, nullptr, nullptr, nullptr, nullptr);

  // ---- GCN stack ----
  launch_gemm(stream, BNROWS, EE, 1, XBF, 128, 0,0, W1T, 128, 0,0,
              TT, 256, 0,0, 128, 0, 5, 0, nullptr, nullptr, nullptr, nullptr);
  launch_gemm(stream, 256, 256, BB, TT, 256, 65536,0, AN, 256, 65536,0,
              GBF, 256, 0,0, 256, 0, 9, 0, b1, mask, GCN, nullptr);
  launch_gemm(stream, BNROWS, EE, 1, GBF, 256, 0,0, W2T, 256, 0,0,
              TT, 256, 0,0, 256, 0, 5, 0, nullptr, nullptr, nullptr, nullptr);
  launch_gemm(stream, 256, 256, BB, TT, 256, 65536,0, AN, 256, 65536,0,
              GBF, 256, 0,0, 256, 0, 9, 1, b2, mask, GCN, nullptr);
  launch_gemm(stream, BNROWS, EE, 1, GBF, 256, 0,0, W3T, 256, 0,0,
              TT, 256, 0,0, 256, 0, 5, 0, nullptr, nullptr, nullptr, nullptr);
  launch_gemm(stream, 256, 256, BB, TT, 256, 65536,0, AN, 256, 65536,0,
              GBF, 256, 0,0, 256, 0, 9, 1, b3, mask, GCN, nullptr);

  // ---- LN1 ----
  ln_kernel<<<4096, 256, 0, stream>>>(GCN, ln1g, ln1b, HBF);

  // ---- attention: combined Q'(=H·ABH^T)/V GEMM -> fused attn -> Y@Wo ----
  launch_gemm(stream, BNROWS, 4096, 1, HBF, 256, 0,0, ABH, 256, 0,0,
              QPB, 2048, 0,0, 256, 0, 15, 0, nullptr, nullptr, nullptr, VT);
  attn_kernel<<<dim3(4, 512), 512, 0, stream>>>(QPB, HBF, VT, DSTB, mask);
  launch_gemm(stream, BNROWS, EE, 1, QPB, 2048, 0,0, WOT, 2048, 0,0,
              U, 256, 0,0, 2048, 0, 12, 0, bo, mask, GCN, nullptr);

  // ---- LN2 + FFN (final residual fused into FFN2 epilogue) ----
  ln_kernel<<<4096, 256, 0, stream>>>(U, ln2g, ln2b, HBF);
  launch_gemm(stream, BNROWS, FFN, 1, HBF, 256, 0,0, WF1T, 256, 0,0,
              FFB, 1024, 0,0, 256, 0, 3, 0, bf1, nullptr, nullptr, nullptr);
  launch_gemm(stream, BNROWS, EE, 1, FFB, 1024, 0,0, WF2T, 1024, 0,0,
              d_out, 256, 0,0, 1024, 0, 8, 0, bf2, mask, GCN, U);
}

// Round 10
// 494.167 us; speedup vs baseline: 1.0622x; 1.0622x over previous
//
#include <hip/hip_runtime.h>
#include <hip/hip_bf16.h>
#include <cmath>

// Problem constants: B=64, N=256, IN=128, E=256, H=8, F=1024
#define BB 64
#define NNODES 256
#define INF_ 128
#define EE 256
#define HH 8
#define FFN 1024
#define BNROWS 16384   // B*N

typedef __attribute__((ext_vector_type(8))) short short8;
typedef __attribute__((ext_vector_type(4))) float floatx4;
typedef __attribute__((ext_vector_type(4))) unsigned short ushort4v;

__device__ __forceinline__ float b2f(unsigned short u) {
  union { unsigned u32; float f; } w; w.u32 = ((unsigned)u) << 16; return w.f;
}
__device__ __forceinline__ unsigned short f2b(float f) {
  union { float f; unsigned u32; } w; w.f = f;
  unsigned r = w.u32 + 0x7FFFu + ((w.u32 >> 16) & 1u);   // RNE
  return (unsigned short)(r >> 16);
}
// tanh-gelu (max abs dev from exact erf-gelu ~3e-4, far below bf16 rounding)
__device__ __forceinline__ float gelu_f(float x) {
  const float z = 0.7978845608028654f * (x + 0.044715f * x * x * x);
  const float e = __expf(2.0f * z);
  const float th = (e - 1.0f) / (e + 1.0f);
  return 0.5f * x * (1.0f + th);
}

typedef const __attribute__((address_space(1))) void GV;
typedef __attribute__((address_space(3))) void LV;

// async global->LDS: per-lane 16B source, wave-uniform LDS base (+lane*16)
__device__ __forceinline__ void gl_lds16(const unsigned short* g,
                                         unsigned short* l, int lane) {
#if __has_builtin(__builtin_amdgcn_global_load_lds)
  __builtin_amdgcn_global_load_lds((GV*)g, (LV*)l, 16, 0, 0);
#else
  *(short8*)(l + lane * 8) = *(const short8*)g;
#endif
}

// ---------------------------------------------------------------------------
// One kernel for ALL packing: transpose-cvt jobs + plain cvt jobs (C==0).
// ---------------------------------------------------------------------------
struct PackArgs {
  const float* src[12];
  unsigned short* dst[12];
  int R[12], C[12];
  int start[13];
};

__launch_bounds__(256)
__global__ void pack_kernel(PackArgs a)
{
  __shared__ float tile[32][33];
  const int bid = blockIdx.x;
  int j = 0;
  while (bid >= a.start[j + 1]) j++;
  const int lb = bid - a.start[j];
  const float* src = a.src[j];
  unsigned short* dst = a.dst[j];
  const int R = a.R[j], C = a.C[j];

  if (C == 0) {      // plain cvt, R = element count
    const int i = (lb * 256 + threadIdx.x) * 4;
    if (i >= R) return;
    floatx4 v = *(const floatx4*)(src + i);
    ushort4v o;
    #pragma unroll
    for (int k = 0; k < 4; k++) o[k] = f2b(v[k]);
    *(ushort4v*)(dst + i) = o;
    return;
  }
  const int tpr = C >> 5;
  const int c0 = (lb % tpr) * 32, r0 = (lb / tpr) * 32;
  const int tx = threadIdx.x & 31, ty = threadIdx.x >> 5;
  #pragma unroll
  for (int i = ty; i < 32; i += 8)
    tile[i][tx] = src[(long long)(r0 + i) * C + c0 + tx];
  __syncthreads();
  #pragma unroll
  for (int i = ty; i < 32; i += 8)
    dst[(long long)(c0 + i) * R + r0 + tx] = f2b(tile[tx][i]);
}

// ---------------------------------------------------------------------------
// dis = rsqrt(clip(rowsum(A),1,inf)); A = adj (f32) with diag forced to 1
// ---------------------------------------------------------------------------
__global__ void deg_kernel(const float* __restrict__ adj,
                           float* __restrict__ dis)
{
  const int g = blockIdx.x * 4 + (threadIdx.x >> 6);
  const int lane = threadIdx.x & 63;
  const int i = g & 255;
  floatx4 v = *(const floatx4*)(adj + (long long)g * 256 + lane * 4);
  float s = 0.f;
  #pragma unroll
  for (int jj = 0; jj < 4; jj++) {
    const int j = lane * 4 + jj;
    s += (j == i) ? 1.0f : v[jj];
  }
  #pragma unroll
  for (int off = 32; off > 0; off >>= 1) s += __shfl_xor(s, off);
  if (lane == 0) dis[g] = 1.0f / sqrtf(fmaxf(s, 1.0f));
}

// An[b,i,j] = bf16(dis_i * A_ij * dis_j)
__global__ void an_kernel(const float* __restrict__ adj,
                          const float* __restrict__ dis,
                          unsigned short* __restrict__ An)
{
  const long long base = ((long long)blockIdx.x * 256 + threadIdx.x) * 4;
  const int rowg = (int)(base >> 8);
  const int i = rowg & 255;
  const int brow = rowg & ~255;
  const int j0 = (int)(base & 255);
  const float di = dis[rowg];
  floatx4 v = *(const floatx4*)(adj + base);
  ushort4v o;
  #pragma unroll
  for (int jj = 0; jj < 4; jj++) {
    const int j = j0 + jj;
    const float a = (j == i) ? 1.0f : v[jj];
    o[jj] = f2b(di * dis[brow + j] * a);
  }
  *(ushort4v*)(An + base) = o;
}

// ---------------------------------------------------------------------------
// Batched bf16 MFMA GEMM, tile 128x128, BK=128 chunks, 512 threads (8 waves,
// 2x4), each wave 64x32 (acc[4][2]). A (M,K) rm; B (N,K) rm (always NT).
// LDS rows x 16 slots of 16B; slot s holds k-octet q = s ^ (r&7) (XOR swizzle).
// modes:
//  0: f32 store | 1: bf16 store | 2: f32 accumulate | 3: bf16 gelu(val+aux1[col])
//  5: TT store: b=row>>8,n=row&255 -> bf16 C[b*65536+col*256+n]
//  8: final:  f32 C[row*256+col] = gcn[i]+attf[i]+(val+aux1[col])*mask[row]
//  9: GCN epi (C'=U^T): token=zb*256+col, feat=row; g=relu((val+aux1[feat])*mask[token]);
//     bf16 C[token*256+feat]=g; gcn[...] (flag? += : =) g
// 12: f32 C[row*256+col] = gcn[idx] + (val + aux1[col]) * mask[row]
// 13: bf16 store of val * 0.0625  (ABH with attention scale folded)
// 15: Q'/V combined: col<2048 -> bf16 C[row*2048+col] (Q');
//     else V^T scatter: z2=(row>>8)*8+((col>>8)-8); bf16
//     aux2[z2*65536+(col&255)*256+(row&255)]
// ---------------------------------------------------------------------------
__launch_bounds__(512, 4)
__global__ void gemm_kernel(const unsigned short* __restrict__ A, int lda,
                            long long sAo, long long sAi,
                            const unsigned short* __restrict__ Bm, int ldb,
                            long long sBo, long long sBi,
                            void* __restrict__ Cv, int ldc,
                            long long sCo, long long sCi,
                            int K, int zshift, int mode, int flag,
                            const float* __restrict__ aux1,
                            const float* __restrict__ mask,
                            float* __restrict__ gcn,
                            void* __restrict__ aux2)
{
  __shared__ __align__(16) unsigned short sA[16384];   // 32KB
  __shared__ __align__(16) unsigned short sB[16384];   // 32KB

  const int t = threadIdx.x;
  const int z = blockIdx.z;
  const int zi = z & ((1 << zshift) - 1);
  const int zb = z >> zshift;
  const int m0 = blockIdx.x * 128;
  const int n0 = blockIdx.y * 128;
  A  += zb * sAo + zi * sAi;
  Bm += zb * sBo + zi * sBi;
  const long long cbase = zb * sCo + zi * sCi;

  const int lane = t & 63;
  const int w = t >> 6;              // wave 0..7
  const int wm = w >> 2, wn = w & 3; // 2 x 4
  const int lm = lane & 15, qd = lane >> 4;

  floatx4 acc[4][2] = {};

  const int sub = lane >> 4;        // 0..3
  const int qs  = lane & 15;        // slot within row
  const unsigned short* pA[4];
  const unsigned short* pB[4];
  #pragma unroll
  for (int i = 0; i < 4; i++) {
    const int d = w * 4 + i;        // DMA index 0..31
    const int r = d * 4 + sub;      // tile row 0..127
    const int co = (qs ^ (r & 7)) * 8;   // swizzled col octet (elements)
    pA[i] = A + (long long)(m0 + r) * lda + co;
    pB[i] = Bm + (long long)(n0 + r) * ldb + co;
  }

  for (int kk = 0; kk < K; kk += 128) {
    #pragma unroll
    for (int i = 0; i < 4; i++) {
      gl_lds16(pA[i] + kk, &sA[(w * 4 + i) * 512], lane);
      gl_lds16(pB[i] + kk, &sB[(w * 4 + i) * 512], lane);
    }
    __syncthreads();

    #pragma unroll
    for (int ks = 0; ks < 4; ks++) {
      short8 af[4], bg[2];
      const int q = ks * 4 + qd;          // k-octet 0..15
      #pragma unroll
      for (int mi = 0; mi < 4; mi++) {
        const int r = wm * 64 + mi * 16 + lm;
        af[mi] = *(const short8*)&sA[r * 128 + ((q ^ (r & 7)) * 8)];
      }
      #pragma unroll
      for (int ni = 0; ni < 2; ni++) {
        const int r = wn * 32 + ni * 16 + lm;
        bg[ni] = *(const short8*)&sB[r * 128 + ((q ^ (r & 7)) * 8)];
      }
      #pragma unroll
      for (int mi = 0; mi < 4; mi++)
        #pragma unroll
        for (int ni = 0; ni < 2; ni++)
          acc[mi][ni] = __builtin_amdgcn_mfma_f32_16x16x32_bf16(
              af[mi], bg[ni], acc[mi][ni], 0, 0, 0);
    }
    __syncthreads();
  }

  // ---- epilogue ----
  #pragma unroll
  for (int mi = 0; mi < 4; mi++) {
    const int row0 = m0 + wm * 64 + mi * 16 + qd * 4;
    #pragma unroll
    for (int ni = 0; ni < 2; ni++) {
      const int col = n0 + wn * 32 + ni * 16 + lm;
      floatx4 a = acc[mi][ni];
      if (mode == 0) {
        float* Cf = (float*)Cv;
        #pragma unroll
        for (int r = 0; r < 4; r++)
          Cf[cbase + (long long)(row0 + r) * ldc + col] = a[r];
      } else if (mode == 1) {
        unsigned short* Cb = (unsigned short*)Cv;
        #pragma unroll
        for (int r = 0; r < 4; r++)
          Cb[cbase + (long long)(row0 + r) * ldc + col] = f2b(a[r]);
      } else if (mode == 2) {
        float* Cf = (float*)Cv;
        #pragma unroll
        for (int r = 0; r < 4; r++)
          Cf[cbase + (long long)(row0 + r) * ldc + col] += a[r];
      } else if (mode == 3) {
        unsigned short* Cb = (unsigned short*)Cv;
        const float bv = aux1[col];
        #pragma unroll
        for (int r = 0; r < 4; r++)
          Cb[cbase + (long long)(row0 + r) * ldc + col] = f2b(gelu_f(a[r] + bv));
      } else if (mode == 5) {
        const int b = row0 >> 8, n = row0 & 255;
        ushort4v o;
        #pragma unroll
        for (int r = 0; r < 4; r++) o[r] = f2b(a[r]);
        *(ushort4v*)((unsigned short*)Cv + (long long)b * 65536 + col * 256 + n) = o;
      } else if (mode == 8) {
        float* Cf = (float*)Cv;
        const float* attf = (const float*)aux2;
        const float bv = aux1[col];
        #pragma unroll
        for (int r = 0; r < 4; r++) {
          const long long idx = (long long)(row0 + r) * 256 + col;
          Cf[idx] = gcn[idx] + attf[idx] + (a[r] + bv) * mask[row0 + r];
        }
      } else if (mode == 9) {
        const int token = zb * 256 + col;
        const float m = mask[token];
        ushort4v o; floatx4 g;
        #pragma unroll
        for (int r = 0; r < 4; r++) {
          const float v = fmaxf((a[r] + aux1[row0 + r]) * m, 0.f);
          o[r] = f2b(v); g[r] = v;
        }
        *(ushort4v*)((unsigned short*)Cv + (long long)token * 256 + row0) = o;
        float* gp = gcn + (long long)token * 256 + row0;
        if (flag) { floatx4 old = *(const floatx4*)gp; g += old; }
        *(floatx4*)gp = g;
      } else if (mode == 12) { // U = GCN + (val + bo)*mask
        float* Cf = (float*)Cv;
        const float bv = aux1[col];
        #pragma unroll
        for (int r = 0; r < 4; r++) {
          const long long idx = (long long)(row0 + r) * 256 + col;
          Cf[idx] = gcn[idx] + (a[r] + bv) * mask[row0 + r];
        }
      } else if (mode == 13) { // scaled bf16 (ABH /16)
        unsigned short* Cb = (unsigned short*)Cv;
        #pragma unroll
        for (int r = 0; r < 4; r++)
          Cb[cbase + (long long)(row0 + r) * ldc + col] = f2b(a[r] * 0.0625f);
      } else { // 15: Q' store / V^T scatter
        if (col < 2048) {
          unsigned short* Cb = (unsigned short*)Cv;
          #pragma unroll
          for (int r = 0; r < 4; r++)
            Cb[(long long)(row0 + r) * 2048 + col] = f2b(a[r]);
        } else {
          const int z2 = (row0 >> 8) * 8 + ((col >> 8) - 8);
          const int e = col & 255, n = row0 & 255;
          ushort4v o;
          #pragma unroll
          for (int r = 0; r < 4; r++) o[r] = f2b(a[r]);
          *(ushort4v*)((unsigned short*)aux2 + (long long)z2 * 65536 + e * 256 + n) = o;
        }
      }
    }
  }
}

// ---------------------------------------------------------------------------
// Fused attention v6: 128-row m-tiles (r8 structure) + LDS-staged Y writeback
// (r9 fix, in two 64-row halves) + XCD-pairing swizzle: 1D grid, blocks i and
// i+8 share the same z (and the same blockIdx%8 -> same XCD under round-robin)
// so H_b/V/dist are L2-deduped between the two m-tiles of each z.
// ---------------------------------------------------------------------------
__launch_bounds__(512, 2)
__global__ void attn_kernel(unsigned short* __restrict__ QP,   // (16384,2048) Q' in / Y out
                            const unsigned short* __restrict__ HBF, // (16384,256)
                            const unsigned short* __restrict__ VT,  // (512,256,256)
                            const unsigned short* __restrict__ DSTB,// (64,256,256) bf16
                            const float* __restrict__ mask)
{
  __shared__ __align__(16) unsigned short sQ[8192];     // 16KB: Q' chunk / P chunk (128x64)
  __shared__ __align__(16) unsigned short sKV[16896];   // 33KB: H/V chunk (256x64) or Y half (64x264)
  __shared__ float redm[4][128];
  __shared__ float reds[4][128];

  const int bi = blockIdx.x;           // 0..1023
  const int z  = (bi >> 4) * 8 + (bi & 7);  // b*8+h ; siblings bi, bi+8
  const int mt = (bi & 15) >> 3;       // 0..1
  const int b  = z >> 3, h = z & 7;
  const int t = threadIdx.x, lane = t & 63, w = t >> 6;
  const int wm = w >> 2, wn = w & 3;   // 2 x 4
  const int lm = lane & 15, qd = lane >> 4;
  const int m0 = mt * 128;

  unsigned short* Qm = QP + ((long long)(b * 256 + m0)) * 2048 + h * 256;
  const unsigned short* Hb = HBF + (long long)b * 65536;
  const unsigned short* Vb = VT + (long long)z * 65536;
  const unsigned short* db = DSTB + (long long)b * 65536;
  const float* maskb = mask + b * 256;

  const int rin = lane >> 3;   // row within DMA (0..7)
  const int qs  = lane & 7;    // octet slot (0..7)

  // ---- S phase: S = Q'_tile * H_b^T, 4 chunks of 64 over e ----
  floatx4 S[4][4] = {};
  for (int c = 0; c < 4; c++) {
    const int e0 = c * 64;
    #pragma unroll
    for (int i = 0; i < 2; i++) {            // Q' chunk: 16 DMAs
      const int d = w * 2 + i;
      const int r = d * 8 + rin;             // tile row 0..127
      gl_lds16(Qm + (long long)r * 2048 + e0 + ((qs ^ (r & 7)) * 8),
               &sQ[d * 512], lane);
    }
    #pragma unroll
    for (int i = 0; i < 4; i++) {            // H_b rows 0..255: 32 DMAs
      const int d = w * 4 + i;
      const int r = d * 8 + rin;
      gl_lds16(Hb + (long long)r * 256 + e0 + ((qs ^ (r & 7)) * 8),
               &sKV[d * 512], lane);
    }
    __syncthreads();
    #pragma unroll
    for (int ks = 0; ks < 2; ks++) {
      short8 af[4], bg4[4];
      const int o = ks * 4 + qd;
      #pragma unroll
      for (int mi = 0; mi < 4; mi++) {
        const int r = wm * 64 + mi * 16 + lm;
        af[mi] = *(const short8*)&sQ[r * 64 + ((o ^ (r & 7)) * 8)];
      }
      #pragma unroll
      for (int ni = 0; ni < 4; ni++) {
        const int r = wn * 64 + ni * 16 + lm;
        bg4[ni] = *(const short8*)&sKV[r * 64 + ((o ^ (r & 7)) * 8)];
      }
      #pragma unroll
      for (int mi = 0; mi < 4; mi++)
        #pragma unroll
        for (int ni = 0; ni < 4; ni++)
          S[mi][ni] = __builtin_amdgcn_mfma_f32_16x16x32_bf16(
              af[mi], bg4[ni], S[mi][ni], 0, 0, 0);
    }
    __syncthreads();
  }

  // ---- prefetch V chunk 0 (softmax hides the latency) ----
  #pragma unroll
  for (int i = 0; i < 4; i++) {
    const int d = w * 4 + i;
    const int r = d * 8 + rin;
    gl_lds16(Vb + (long long)r * 256 + ((qs ^ (r & 7)) * 8),
             &sKV[d * 512], lane);
  }

  // ---- softmax over cols (keys); dist is bf16 ----
  float mk[4];
  #pragma unroll
  for (int ni = 0; ni < 4; ni++) mk[ni] = maskb[wn * 64 + ni * 16 + lm];

  float lred[4][4];
  #pragma unroll
  for (int mi = 0; mi < 4; mi++) {
    #pragma unroll
    for (int r = 0; r < 4; r++) {
      const int row = wm * 64 + mi * 16 + qd * 4 + r;
      const float mq = maskb[m0 + row];
      float mx = -3e38f;
      #pragma unroll
      for (int ni = 0; ni < 4; ni++) {
        const int col = wn * 64 + ni * 16 + lm;
        const float dv = b2f(db[(long long)(m0 + row) * 256 + col]);
        const float v = (mq != 0.f && mk[ni] != 0.f) ? (S[mi][ni][r] + dv) : -1e9f;
        S[mi][ni][r] = v;
        mx = fmaxf(mx, v);
      }
      lred[mi][r] = mx;
    }
  }
  #pragma unroll
  for (int off = 1; off < 16; off <<= 1)
    #pragma unroll
    for (int mi = 0; mi < 4; mi++)
      #pragma unroll
      for (int r = 0; r < 4; r++)
        lred[mi][r] = fmaxf(lred[mi][r], __shfl_xor(lred[mi][r], off));
  if (lm == 0)
    #pragma unroll
    for (int mi = 0; mi < 4; mi++)
      #pragma unroll
      for (int r = 0; r < 4; r++)
        redm[wn][wm * 64 + mi * 16 + qd * 4 + r] = lred[mi][r];
  __syncthreads();

  #pragma unroll
  for (int mi = 0; mi < 4; mi++) {
    #pragma unroll
    for (int r = 0; r < 4; r++) {
      const int row = wm * 64 + mi * 16 + qd * 4 + r;
      const float gmax = fmaxf(fmaxf(redm[0][row], redm[1][row]),
                               fmaxf(redm[2][row], redm[3][row]));
      float s = 0.f;
      #pragma unroll
      for (int ni = 0; ni < 4; ni++) {
        const float e = __expf(S[mi][ni][r] - gmax);   // invalid -> exactly 0
        S[mi][ni][r] = e;
        s += e;
      }
      lred[mi][r] = s;
    }
  }
  #pragma unroll
  for (int off = 1; off < 16; off <<= 1)
    #pragma unroll
    for (int mi = 0; mi < 4; mi++)
      #pragma unroll
      for (int r = 0; r < 4; r++)
        lred[mi][r] += __shfl_xor(lred[mi][r], off);
  if (lm == 0)
    #pragma unroll
    for (int mi = 0; mi < 4; mi++)
      #pragma unroll
      for (int r = 0; r < 4; r++)
        reds[wn][wm * 64 + mi * 16 + qd * 4 + r] = lred[mi][r];
  __syncthreads();

  #pragma unroll
  for (int mi = 0; mi < 4; mi++) {
    #pragma unroll
    for (int r = 0; r < 4; r++) {
      const int row = wm * 64 + mi * 16 + qd * 4 + r;
      const float gs = reds[0][row] + reds[1][row] + reds[2][row] + reds[3][row];
      const float inv = 1.0f / gs;
      #pragma unroll
      for (int ni = 0; ni < 4; ni++) S[mi][ni][r] *= inv;
    }
  }

  // ---- PV phase: 4 chunks over keys; V_{c+1} issued post-barrier ----
  floatx4 Y[4][4] = {};
  for (int c = 0; c < 4; c++) {
    if (wn == c) {                          // write P chunk
      #pragma unroll
      for (int mi = 0; mi < 4; mi++)
        #pragma unroll
        for (int r = 0; r < 4; r++) {
          const int row = wm * 64 + mi * 16 + qd * 4 + r;
          #pragma unroll
          for (int ni = 0; ni < 4; ni++) {
            const int kl = ni * 16 + lm;
            const int slot = (kl >> 3) ^ (row & 7);
            sQ[row * 64 + slot * 8 + (kl & 7)] = f2b(S[mi][ni][r]);
          }
        }
    }
    __syncthreads();                        // P_c visible; V_c drained
    #pragma unroll
    for (int ks = 0; ks < 2; ks++) {
      short8 af[4], bg4[4];
      const int o = ks * 4 + qd;
      #pragma unroll
      for (int mi = 0; mi < 4; mi++) {
        const int r = wm * 64 + mi * 16 + lm;
        af[mi] = *(const short8*)&sQ[r * 64 + ((o ^ (r & 7)) * 8)];
      }
      #pragma unroll
      for (int ni = 0; ni < 4; ni++) {
        const int r = wn * 64 + ni * 16 + lm;
        bg4[ni] = *(const short8*)&sKV[r * 64 + ((o ^ (r & 7)) * 8)];
      }
      #pragma unroll
      for (int mi = 0; mi < 4; mi++)
        #pragma unroll
        for (int ni = 0; ni < 4; ni++)
          Y[mi][ni] = __builtin_amdgcn_mfma_f32_16x16x32_bf16(
              af[mi], bg4[ni], Y[mi][ni], 0, 0, 0);
    }
    __syncthreads();
    if (c < 3) {
      #pragma unroll
      for (int i = 0; i < 4; i++) {
        const int d = w * 4 + i;
        const int r = d * 8 + rin;
        gl_lds16(Vb + (long long)r * 256 + (c + 1) * 64 + ((qs ^ (r & 7)) * 8),
                 &sKV[d * 512], lane);
      }
    }
  }

  // ---- epilogue: Y -> LDS (stride 264, two 64-row halves) -> 16B stores ----
  #pragma unroll
  for (int half = 0; half < 2; half++) {
    __syncthreads();
    if (wm == half) {
      #pragma unroll
      for (int mi = 0; mi < 4; mi++)
        #pragma unroll
        for (int ni = 0; ni < 4; ni++) {
          const int col = wn * 64 + ni * 16 + lm;
          #pragma unroll
          for (int r = 0; r < 4; r++) {
            const int rl = mi * 16 + qd * 4 + r;    // 0..63
            sKV[rl * 264 + col] = f2b(Y[mi][ni][r]);
          }
        }
    }
    __syncthreads();
    #pragma unroll
    for (int it = 0; it < 4; it++) {
      const int idx = it * 512 + t;        // 0..2047 = 64 rows x 32 x 16B
      const int row = idx >> 5, u = idx & 31;
      short8 v = *(const short8*)&sKV[row * 264 + u * 8];
      *(short8*)(Qm + (long long)(half * 64 + row) * 2048 + u * 8) = v;
    }
  }
}

// ---------------------------------------------------------------------------
__global__ void ln_kernel(const float* __restrict__ X,
                          const float* __restrict__ gam,
                          const float* __restrict__ bet,
                          unsigned short* __restrict__ out)
{
  const int g = blockIdx.x * 4 + (threadIdx.x >> 6);
  const int lane = threadIdx.x & 63;
  floatx4 v = *(const floatx4*)(X + (long long)g * 256 + lane * 4);
  float s = v[0] + v[1] + v[2] + v[3];
  float sq = v[0]*v[0] + v[1]*v[1] + v[2]*v[2] + v[3]*v[3];
  #pragma unroll
  for (int off = 32; off > 0; off >>= 1) {
    s  += __shfl_xor(s, off);
    sq += __shfl_xor(sq, off);
  }
  const float mean = s * (1.0f / 256.0f);
  const float var = sq * (1.0f / 256.0f) - mean * mean;
  const float rs = 1.0f / sqrtf(var + 1e-5f);
  ushort4v o;
  #pragma unroll
  for (int jj = 0; jj < 4; jj++) {
    const int c = lane * 4 + jj;
    o[jj] = f2b((v[jj] - mean) * rs * gam[c] + bet[c]);
  }
  *(ushort4v*)(out + (long long)g * 256 + lane * 4) = o;
}

// ---------------------------------------------------------------------------
static inline void launch_gemm(hipStream_t st, int M, int N, int batch,
    const void* A, int lda, long long sAo, long long sAi,
    const void* B, int ldb, long long sBo, long long sBi,
    void* C, int ldc, long long sCo, long long sCi,
    int K, int zshift, int mode, int flag,
    const float* aux1, const float* mask, float* gcn, void* aux2)
{
  dim3 grid(M / 128, N / 128, batch), blk(512);
  gemm_kernel<<<grid, blk, 0, st>>>(
      (const unsigned short*)A, lda, sAo, sAi,
      (const unsigned short*)B, ldb, sBo, sBi,
      C, ldc, sCo, sCi, K, zshift, mode, flag, aux1, mask, gcn, aux2);
}

extern "C" void kernel_launch(void* const* d_in, const int* in_sizes, int n_in,
                              void* d_out, int out_size, void* d_ws, size_t ws_size,
                              hipStream_t stream)
{
  (void)in_sizes; (void)n_in; (void)out_size;
  const float* x    = (const float*)d_in[0];
  const float* adj  = (const float*)d_in[1];
  const float* mask = (const float*)d_in[2];
  const float* dist = (const float*)d_in[3];
  const float* W1   = (const float*)d_in[4];
  const float* b1   = (const float*)d_in[5];
  const float* W2   = (const float*)d_in[6];
  const float* b2   = (const float*)d_in[7];
  const float* W3   = (const float*)d_in[8];
  const float* b3   = (const float*)d_in[9];
  const float* ln1g = (const float*)d_in[10];
  const float* ln1b = (const float*)d_in[11];
  const float* Wq   = (const float*)d_in[12];
  const float* Wk   = (const float*)d_in[13];
  const float* Wv   = (const float*)d_in[14];
  const float* Wo   = (const float*)d_in[15];
  const float* bo   = (const float*)d_in[16];
  const float* ln2g = (const float*)d_in[17];
  const float* ln2b = (const float*)d_in[18];
  const float* Wf1  = (const float*)d_in[19];
  const float* bf1  = (const float*)d_in[20];
  const float* Wf2  = (const float*)d_in[21];
  const float* bf2  = (const float*)d_in[22];

  char* w = (char*)d_ws;
  auto alloc = [&](size_t sz) { void* p = (void*)w; w += sz; return p; };
  // persistent (~61 MB)
  unsigned short* W1T   = (unsigned short*)alloc(65536);      // (256,128)
  unsigned short* W2T   = (unsigned short*)alloc(131072);     // (256,256)
  unsigned short* W3T   = (unsigned short*)alloc(131072);
  unsigned short* ABH   = (unsigned short*)alloc(1048576);    // (2048,256) = Wk_h Wq_h^T /16
  unsigned short* WVT   = (unsigned short*)alloc(1048576);    // (2048,256)
  unsigned short* WOT   = (unsigned short*)alloc(1048576);    // (256,2048)
  unsigned short* WF1T  = (unsigned short*)alloc(524288);     // (1024,256)
  unsigned short* WF2T  = (unsigned short*)alloc(524288);     // (256,1024)
  unsigned short* WQb   = (unsigned short*)alloc(1048576);    // (256,2048) plain
  unsigned short* WKb   = (unsigned short*)alloc(1048576);    // (256,2048) plain
  unsigned short* XBF   = (unsigned short*)alloc(4194304);    // (16384,128)
  unsigned short* DSTB  = (unsigned short*)alloc(8388608);    // (64,256,256) bf16 dist
  float*          GCN   = (float*)         alloc(16777216);   // (16384,256)
  float*          U     = (float*)         alloc(16777216);   // ATT f32
  unsigned short* HBF   = (unsigned short*)alloc(8388608);    // (16384,256)
  float*          DIS   = (float*)         alloc(65536);
  // scratch union (peak = attention: 134.2 MB)
  char* scratch = (char*)alloc(134217728);
  if ((size_t)(w - (char*)d_ws) > ws_size) return;
  // gcn phase views
  unsigned short* AN  = (unsigned short*)scratch;              // 8.4 MB
  unsigned short* TT  = (unsigned short*)(scratch + 8388608);  // 8.4 MB
  unsigned short* GBF = (unsigned short*)(scratch + 16777216); // 8.4 MB
  // attention phase views
  unsigned short* QPB = (unsigned short*)scratch;                 // (16384,2048) 67 MB  Q'->Y
  unsigned short* VT  = (unsigned short*)(scratch + 67108864);    // (512,256,256) 67 MB
  // ffn phase view
  unsigned short* FFB = (unsigned short*)scratch;                 // 33.6 MB

  // ---- single packing launch: 7 transposes + 4 plain cvts ----
  PackArgs pa;
  const float* srcs[11] = {W1, W2, W3, Wv, Wo, Wf1, Wf2, x, Wq, Wk, dist};
  unsigned short* dsts[11] = {W1T, W2T, W3T, WVT, WOT, WF1T, WF2T, XBF, WQb, WKb, DSTB};
  const int Rs[11] = {128, 256, 256, 256, 2048, 256, 1024,
                      BNROWS * INF_, EE * HH * EE, EE * HH * EE, BB * 65536};
  const int Cs[11] = {256, 256, 256, 2048, 256, 1024, 256, 0, 0, 0, 0};
  const int sts[12] = {0, 32, 96, 160, 672, 1184, 1440, 1696, 3744, 4256, 4768, 8864};
  for (int j = 0; j < 11; j++) {
    pa.src[j] = srcs[j]; pa.dst[j] = dsts[j]; pa.R[j] = Rs[j]; pa.C[j] = Cs[j];
  }
  for (int j = 0; j < 12; j++) pa.start[j] = sts[j];
  pack_kernel<<<8864, 256, 0, stream>>>(pa);

  // ---- adjacency normalization ----
  deg_kernel<<<4096, 256, 0, stream>>>(adj, DIS);
  an_kernel<<<4096, 256, 0, stream>>>(adj, DIS, AN);

  // ---- ABH_h = Wk_h Wq_h^T / 16  (8 heads, tiny batched GEMM) ----
  launch_gemm(stream, 256, 256, 8, WKb, 2048, 256, 0, WQb, 2048, 256, 0,
              ABH, 256, 65536, 0, 256, 0, 13, 0, nullptr, nullptr, nullptr, nullptr);

  // ---- GCN stack ----
  launch_gemm(stream, BNROWS, EE, 1, XBF, 128, 0,0, W1T, 128, 0,0,
              TT, 256, 0,0, 128, 0, 5, 0, nullptr, nullptr, nullptr, nullptr);
  launch_gemm(stream, 256, 256, BB, TT, 256, 65536,0, AN, 256, 65536,0,
              GBF, 256, 0,0, 256, 0, 9, 0, b1, mask, GCN, nullptr);
  launch_gemm(stream, BNROWS, EE, 1, GBF, 256, 0,0, W2T, 256, 0,0,
              TT, 256, 0,0, 256, 0, 5, 0, nullptr, nullptr, nullptr, nullptr);
  launch_gemm(stream, 256, 256, BB, TT, 256, 65536,0, AN, 256, 65536,0,
              GBF, 256, 0,0, 256, 0, 9, 1, b2, mask, GCN, nullptr);
  launch_gemm(stream, BNROWS, EE, 1, GBF, 256, 0,0, W3T, 256, 0,0,
              TT, 256, 0,0, 256, 0, 5, 0, nullptr, nullptr, nullptr, nullptr);
  launch_gemm(stream, 256, 256, BB, TT, 256, 65536,0, AN, 256, 65536,0,
              GBF, 256, 0,0, 256, 0, 9, 1, b3, mask, GCN, nullptr);

  // ---- LN1 ----
  ln_kernel<<<4096, 256, 0, stream>>>(GCN, ln1g, ln1b, HBF);

  // ---- attention: combined Q'(=H·ABH^T)/V GEMM -> fused attn -> Y@Wo ----
  launch_gemm(stream, BNROWS, 4096, 1, HBF, 256, 0,0, ABH, 256, 0,0,
              QPB, 2048, 0,0, 256, 0, 15, 0, nullptr, nullptr, nullptr, VT);
  attn_kernel<<<1024, 512, 0, stream>>>(QPB, HBF, VT, DSTB, mask);
  launch_gemm(stream, BNROWS, EE, 1, QPB, 2048, 0,0, WOT, 2048, 0,0,
              U, 256, 0,0, 2048, 0, 12, 0, bo, mask, GCN, nullptr);

  // ---- LN2 + FFN (final residual fused into FFN2 epilogue) ----
  ln_kernel<<<4096, 256, 0, stream>>>(U, ln2g, ln2b, HBF);
  launch_gemm(stream, BNROWS, FFN, 1, HBF, 256, 0,0, WF1T, 256, 0,0,
              FFB, 1024, 0,0, 256, 0, 3, 0, bf1, nullptr, nullptr, nullptr);
  launch_gemm(stream, BNROWS, EE, 1, FFB, 1024, 0,0, WF2T, 1024, 0,0,
              d_out, 256, 0,0, 1024, 0, 8, 0, bf2, mask, GCN, U);
}